// Round 1
// baseline (431.925 us; speedup 1.0000x reference)
//
#include <hip/hip_runtime.h>

// out[n][h] = sum_k x[n][k] * W[h][k] + b[h]
// N = 4194304 rows, K = 64, H = 64, fp32 in/out, bf16 MFMA compute.

typedef short bf16x8 __attribute__((ext_vector_type(8)));   // 8 bf16 in 4 VGPRs
typedef float f32x4  __attribute__((ext_vector_type(4)));

#define N_ROWS        4194304
#define ROWS_PER_BLK  512          // 4 waves * 16 rows * 8 passes
#define PASSES        8
#define NUM_BLOCKS    (N_ROWS / ROWS_PER_BLK)   // 8192

static __device__ __forceinline__ unsigned short f2bf(float f) {
    // round-to-nearest-even fp32 -> bf16 (inputs are finite normals)
    unsigned int u = __builtin_bit_cast(unsigned int, f);
    u += 0x7FFFu + ((u >> 16) & 1u);
    return (unsigned short)(u >> 16);
}

static __device__ __forceinline__ bf16x8 pack_bf16x8(f32x4 lo, f32x4 hi) {
    bf16x8 r;
    r[0] = (short)f2bf(lo[0]); r[1] = (short)f2bf(lo[1]);
    r[2] = (short)f2bf(lo[2]); r[3] = (short)f2bf(lo[3]);
    r[4] = (short)f2bf(hi[0]); r[5] = (short)f2bf(hi[1]);
    r[6] = (short)f2bf(hi[2]); r[7] = (short)f2bf(hi[3]);
    return r;
}

__global__ __launch_bounds__(256) void
leaf_linear_kernel(const float* __restrict__ x,
                   const float* __restrict__ W,
                   const float* __restrict__ b,
                   float* __restrict__ out) {
    const int tid  = threadIdx.x;
    const int wave = tid >> 6;          // 0..3
    const int lane = tid & 63;
    const int lr   = lane & 15;         // A-row within 16 / B,D-col within 16
    const int g    = lane >> 4;         // 0..3 -> k group (8 elems each)

    // ---- W fragments (B operand), loaded once per wave; W is L2-resident ----
    // B[k][n] = W[n][k]; lane holds n = 16*t + lr, k = 32*s + 8*g + j (j=0..7)
    bf16x8 bw[4][2];
    float  bias[4];
#pragma unroll
    for (int t = 0; t < 4; ++t) {
        bias[t] = b[t * 16 + lr];
#pragma unroll
        for (int s = 0; s < 2; ++s) {
            const float* wp = W + (t * 16 + lr) * 64 + s * 32 + g * 8;
            f32x4 w0 = *(const f32x4*)(wp);
            f32x4 w1 = *(const f32x4*)(wp + 4);
            bw[t][s] = pack_bf16x8(w0, w1);
        }
    }

    // ---- per-pass pointers ----
    // rows covered by this block: [blockIdx.x*512, +512); per pass 64 rows (16/wave)
    long long blk_row0 = (long long)blockIdx.x * ROWS_PER_BLK;
    const float* xp = x + (blk_row0 + wave * 16 + lr) * 64 + g * 8;  // A: this lane's row
    float*       op = out + (blk_row0 + wave * 16) * 64;             // wave tile base

#pragma unroll
    for (int p = 0; p < PASSES; ++p) {
        // ---- load A tile: lane holds x[row][k], k = 8g+{0..7} and 32+8g+{0..7}
        f32x4 a0 = *(const f32x4*)(xp + 0);
        f32x4 a1 = *(const f32x4*)(xp + 4);
        f32x4 a2 = *(const f32x4*)(xp + 32);
        f32x4 a3 = *(const f32x4*)(xp + 36);
        bf16x8 af[2];
        af[0] = pack_bf16x8(a0, a1);   // k-step 0 (k = 8g..8g+7)
        af[1] = pack_bf16x8(a2, a3);   // k-step 1 (k = 32+8g..+7)

        // ---- accumulate: D[16x16] per col-tile t, bias in C (depends on col only)
        f32x4 acc[4];
#pragma unroll
        for (int t = 0; t < 4; ++t)
            acc[t] = (f32x4){bias[t], bias[t], bias[t], bias[t]};
#pragma unroll
        for (int t = 0; t < 4; ++t) {
#pragma unroll
            for (int s = 0; s < 2; ++s)
                acc[t] = __builtin_amdgcn_mfma_f32_16x16x32_bf16(af[s], bw[t][s], acc[t], 0, 0, 0);
        }

        // ---- store: D row = 4*g + reg, col = 16*t + lr
#pragma unroll
        for (int t = 0; t < 4; ++t) {
#pragma unroll
            for (int r = 0; r < 4; ++r)
                op[(4 * g + r) * 64 + 16 * t + lr] = acc[t][r];
        }

        xp += 64 * 64;   // advance 64 rows
        op += 64 * 64;
    }
}

extern "C" void kernel_launch(void* const* d_in, const int* in_sizes, int n_in,
                              void* d_out, int out_size, void* d_ws, size_t ws_size,
                              hipStream_t stream) {
    const float* x = (const float*)d_in[0];
    const float* W = (const float*)d_in[1];
    const float* b = (const float*)d_in[2];
    float* out = (float*)d_out;
    leaf_linear_kernel<<<NUM_BLOCKS, 256, 0, stream>>>(x, W, b, out);
}